// Round 5
// baseline (74.151 us; speedup 1.0000x reference)
//
#include <hip/hip_runtime.h>
#include <math.h>

// KANLinear forward, MI355X — fused single kernel.
// out[b,i,o] = silu( (x@W)[b,o] + sum_k basis[b,i,k] * sw[i,o,k] )
// b=1024, i=256, o=256, k=7. Output 268MB f32, write-bound.
// Design: 256 blocks (1/CU) x 512 threads. Block owns 4 b-rows x all 256 i.
// Store order: i-band outer, bb inner -> 32KB contiguous runs (fill-like stream).

#define NF 256
#define BROWS 4
#define G 4  // i-rows per wave per group step

typedef float f32x4 __attribute__((ext_vector_type(4)));

__device__ __forceinline__ float silu_f(float z) {
    float e = __expf(-z);
    return z * __builtin_amdgcn_rcpf(1.0f + e);
}

__global__ __launch_bounds__(512, 2) void kan_fused(const float* __restrict__ x,
                                                    const float* __restrict__ W,
                                                    const float* __restrict__ sw,
                                                    const float* __restrict__ grid,
                                                    float* __restrict__ out) {
    const int b0 = blockIdx.x * BROWS;
    const int tid = threadIdx.x;

    __shared__ float xs[BROWS][NF];      // 4 KB
    __shared__ float base_s[BROWS][NF];  // 4 KB
    __shared__ float bas[BROWS][NF][8];  // 32 KB

    // ---- load 4 x-rows into LDS ----
    if (tid < 256) {
        const int row = tid >> 6;
        const int c4 = (tid & 63) * 4;
        *reinterpret_cast<f32x4*>(&xs[row][c4]) =
            *reinterpret_cast<const f32x4*>(&x[(size_t)(b0 + row) * NF + c4]);
    }
    __syncthreads();

    // ---- Phase 1: base rows = x @ W (4 x 256) ----
    {
        const int o = tid & 255;
        const int h = tid >> 8;  // 0/1 -> rows {0,1} / {2,3}
        float acc0 = 0.f, acc1 = 0.f;
#pragma unroll 16
        for (int k = 0; k < NF; ++k) {
            const float w = W[k * NF + o];
            acc0 += xs[2 * h + 0][k] * w;
            acc1 += xs[2 * h + 1][k] * w;
        }
        base_s[2 * h + 0][o] = acc0;
        base_s[2 * h + 1][o] = acc1;
    }

    // ---- Phase 2: B-spline basis for (bb, i); each thread does 2 pairs ----
    {
        const int i = tid & 255;
        const int hh = tid >> 8;  // 0/1
        const float g0 = grid[0 * NF + i];
        const float g1 = grid[1 * NF + i];
        const float g2 = grid[2 * NF + i];
        const float g3 = grid[3 * NF + i];
        const float g4 = grid[4 * NF + i];
        const float L = 2.f * g0 - g3;
        const float R = 2.f * g4 - g1;
        const float eg[11] = {L, L, L, g0, g1, g2, g3, g4, R, R, R};

#pragma unroll
        for (int rep = 0; rep < 2; ++rep) {
            const int bb = hh + 2 * rep;  // covers 0..3 across hh,rep
            const float xv = xs[bb][i];

            float B0[10];
#pragma unroll
            for (int t = 0; t < 10; ++t)
                B0[t] = (xv >= eg[t] && xv < eg[t + 1]) ? 1.f : 0.f;
            float B1[9];
#pragma unroll
            for (int t = 0; t < 9; ++t) {
                const float dl = eg[t + 1] - eg[t];
                const float dr = eg[t + 2] - eg[t + 1];
                const float lt = (dl != 0.f) ? (xv - eg[t]) / dl : 0.f;
                const float rt = (dr != 0.f) ? (eg[t + 2] - xv) / dr : 0.f;
                B1[t] = lt * B0[t] + rt * B0[t + 1];
            }
            float B2[8];
#pragma unroll
            for (int t = 0; t < 8; ++t) {
                const float dl = eg[t + 2] - eg[t];
                const float dr = eg[t + 3] - eg[t + 1];
                const float lt = (dl != 0.f) ? (xv - eg[t]) / dl : 0.f;
                const float rt = (dr != 0.f) ? (eg[t + 3] - xv) / dr : 0.f;
                B2[t] = lt * B1[t] + rt * B1[t + 1];
            }
#pragma unroll
            for (int k = 0; k < 7; ++k) bas[bb][i][k] = B2[k];
            bas[bb][i][7] = 0.f;
        }
    }
    __syncthreads();

    // ---- Main loop: write-linear order ----
    const int lane = tid & 63;
    const int wv = tid >> 6;  // 0..7
    const int o4 = lane * 4;

    f32x4 bs[BROWS];
#pragma unroll
    for (int bb = 0; bb < BROWS; ++bb)
        bs[bb] = *reinterpret_cast<const f32x4*>(&base_s[bb][o4]);

    for (int gs = 0; gs < NF / (8 * G); ++gs) {  // 8 group-steps
        // preload sw for this wave's G i-rows (28 floats each = 7 dwordx4)
        f32x4 q[G][7];
#pragma unroll
        for (int j = 0; j < G; ++j) {
            const int i = (gs * G + j) * 8 + wv;
            const f32x4* p4 =
                reinterpret_cast<const f32x4*>(&sw[((size_t)i * NF + o4) * 7]);
#pragma unroll
            for (int kk = 0; kk < 7; ++kk) q[j][kk] = p4[kk];
        }

#pragma unroll
        for (int bb = 0; bb < BROWS; ++bb) {
#pragma unroll
            for (int j = 0; j < G; ++j) {
                const int i = (gs * G + j) * 8 + wv;
                const f32x4 bl = *reinterpret_cast<const f32x4*>(&bas[bb][i][0]);
                const f32x4 bh = *reinterpret_cast<const f32x4*>(&bas[bb][i][4]);
                const float bk[7] = {bl.x, bl.y, bl.z, bl.w, bh.x, bh.y, bh.z};
                // repack q[j] (layout [oo][k], k innermost) into s[oo*7+k]
                float s[28];
#pragma unroll
                for (int m = 0; m < 7; ++m) {
                    s[m * 4 + 0] = q[j][m].x;
                    s[m * 4 + 1] = q[j][m].y;
                    s[m * 4 + 2] = q[j][m].z;
                    s[m * 4 + 3] = q[j][m].w;
                }
                float a0 = bs[bb].x, a1 = bs[bb].y, a2 = bs[bb].z, a3 = bs[bb].w;
#pragma unroll
                for (int k = 0; k < 7; ++k) {
                    a0 += bk[k] * s[0 * 7 + k];
                    a1 += bk[k] * s[1 * 7 + k];
                    a2 += bk[k] * s[2 * 7 + k];
                    a3 += bk[k] * s[3 * 7 + k];
                }
                f32x4 o4v;
                o4v.x = silu_f(a0);
                o4v.y = silu_f(a1);
                o4v.z = silu_f(a2);
                o4v.w = silu_f(a3);
                *reinterpret_cast<f32x4*>(
                    &out[((size_t)(b0 + bb) * NF + i) * NF + o4]) = o4v;
            }
        }
    }
}

extern "C" void kernel_launch(void* const* d_in, const int* in_sizes, int n_in,
                              void* d_out, int out_size, void* d_ws, size_t ws_size,
                              hipStream_t stream) {
    const float* x    = (const float*)d_in[0];  // (1024, 256)
    const float* bw   = (const float*)d_in[1];  // (256, 256)
    const float* sw   = (const float*)d_in[2];  // (256, 256, 7)
    const float* grid = (const float*)d_in[3];  // (5, 256)
    float* out = (float*)d_out;                 // (1024, 256, 256)

    kan_fused<<<dim3(256), 512, 0, stream>>>(x, bw, sw, grid, out);
}